// Round 1
// baseline (301.080 us; speedup 1.0000x reference)
//
#include <hip/hip_runtime.h>
#include <math.h>
#include <stddef.h>

#define BB 1024
#define LL 2048
#define EE 16
#define DD 48    // F*E
#define N1 200
#define N2 80

// ---------------- Kernel A: embed + attention pooling + X_series/mask write ----------------
// one block per batch row, 256 threads, 8 positions per thread
__global__ __launch_bounds__(256) void pool_kernel(
    const int* __restrict__ ig, const int* __restrict__ ish, const int* __restrict__ ic,
    const int* __restrict__ vg, const int* __restrict__ vs, const int* __restrict__ vc,
    const float* __restrict__ emb,
    float* __restrict__ Xs,    // [B,L,48] (part of d_out)
    float* __restrict__ Msk,   // [B,L]   (part of d_out)
    float* __restrict__ X)     // [B,96]  (ws)
{
    const int b   = blockIdx.x;
    const int tid = threadIdx.x;

    __shared__ float item[DD];
    if (tid < DD) {
        int f = tid >> 4, e = tid & 15;
        int id = (f == 0) ? ig[b] : (f == 1) ? ish[b] : ic[b];
        item[tid] = emb[(size_t)id * EE + e];
    }
    __syncthreads();

    // private copy of the (block-uniform) item vector to avoid per-iter LDS reads
    float itr[DD];
#pragma unroll
    for (int j = 0; j < DD; ++j) itr[j] = item[j];

    const float4* __restrict__ emb4 = (const float4*)emb;
    float4* __restrict__ Xs4 = (float4*)(Xs + (size_t)b * LL * DD);
    const int* vgb = vg + (size_t)b * LL;
    const int* vsb = vs + (size_t)b * LL;
    const int* vcb = vc + (size_t)b * LL;
    float* mb = Msk + (size_t)b * LL;

    float pooled[DD];
#pragma unroll
    for (int j = 0; j < DD; ++j) pooled[j] = 0.f;

    for (int it = 0; it < LL / 256; ++it) {
        const int l = tid + it * 256;
        int ids[3];
        ids[0] = vgb[l];
        ids[1] = vsb[l];
        ids[2] = vcb[l];

        // pass 1: gather, store to X_series, accumulate score
        float score = 0.f;
#pragma unroll
        for (int f = 0; f < 3; ++f) {
            const float4* base = emb4 + (size_t)ids[f] * 4;
#pragma unroll
            for (int q = 0; q < 4; ++q) {
                float4 v = base[q];
                Xs4[(size_t)l * 12 + f * 4 + q] = v;
                int j = f * 16 + q * 4;
                score += v.x * itr[j] + v.y * itr[j + 1] + v.z * itr[j + 2] + v.w * itr[j + 3];
            }
        }
        float msk = (ids[0] != 0) ? 1.f : 0.f;
        mb[l] = msk;
        float sm = score * msk;

        // pass 2: reload (L1/L2 hit) and accumulate pooled
#pragma unroll
        for (int f = 0; f < 3; ++f) {
            const float4* base = emb4 + (size_t)ids[f] * 4;
#pragma unroll
            for (int q = 0; q < 4; ++q) {
                float4 v = base[q];
                int j = f * 16 + q * 4;
                pooled[j]     += sm * v.x;
                pooled[j + 1] += sm * v.y;
                pooled[j + 2] += sm * v.z;
                pooled[j + 3] += sm * v.w;
            }
        }
    }

    // reduce pooled[48] across 256 threads: wave shuffle, then 4-wave LDS combine
#pragma unroll
    for (int j = 0; j < DD; ++j) {
        float v = pooled[j];
        for (int off = 32; off; off >>= 1) v += __shfl_xor(v, off);
        pooled[j] = v;
    }
    __shared__ float wsum[4][DD];
    const int wave = tid >> 6, lane = tid & 63;
    if (lane == 0) {
#pragma unroll
        for (int j = 0; j < DD; ++j) wsum[wave][j] = pooled[j];
    }
    __syncthreads();
    if (tid < DD) {
        float s = wsum[0][tid] + wsum[1][tid] + wsum[2][tid] + wsum[3][tid];
        X[(size_t)b * 96 + tid]      = item[tid]; // X_item part
        X[(size_t)b * 96 + DD + tid] = s;         // pooled part
    }
}

// ---------------- Kernel B: H1 = LN(X @ W1 + b1) ----------------
__global__ __launch_bounds__(256) void mlp1_kernel(
    const float* __restrict__ X, const float* __restrict__ W1,
    const float* __restrict__ b1, const float* __restrict__ g1, const float* __restrict__ be1,
    float* __restrict__ H1)
{
    const int b = blockIdx.x, tid = threadIdx.x;
    __shared__ float xr[96];
    if (tid < 96) xr[tid] = X[(size_t)b * 96 + tid];
    __syncthreads();

    float y = 0.f;
    if (tid < N1) {
        y = b1[tid];
        for (int k = 0; k < 96; ++k) y += xr[k] * W1[k * N1 + tid];
    }

    __shared__ float red[256], red2[256];
    float yy = (tid < N1) ? y : 0.f;
    red[tid] = yy; red2[tid] = yy * yy;
    __syncthreads();
    for (int s = 128; s; s >>= 1) {
        if (tid < s) { red[tid] += red[tid + s]; red2[tid] += red2[tid + s]; }
        __syncthreads();
    }
    __shared__ float msh, ish;
    if (tid == 0) {
        float m = red[0] / (float)N1;
        float v = red2[0] / (float)N1 - m * m;
        msh = m; ish = rsqrtf(v + 1e-3f);
    }
    __syncthreads();
    if (tid < N1) H1[(size_t)b * N1 + tid] = g1[tid] * (y - msh) * ish + be1[tid];
}

// ---------------- Kernel C: per-column batch stats (mean, 1/sqrt(var+eps)) ----------------
__global__ __launch_bounds__(256) void colstats_kernel(
    const float* __restrict__ H, int n, int rows,
    float* __restrict__ mout, float* __restrict__ isout)
{
    const int f = blockIdx.x, tid = threadIdx.x;
    float s = 0.f, s2 = 0.f;
    for (int r = tid; r < rows; r += 256) {
        float v = H[(size_t)r * n + f];
        s += v; s2 += v * v;
    }
    __shared__ float red[256], red2[256];
    red[tid] = s; red2[tid] = s2;
    __syncthreads();
    for (int st = 128; st; st >>= 1) {
        if (tid < st) { red[tid] += red[tid + st]; red2[tid] += red2[tid + st]; }
        __syncthreads();
    }
    if (tid == 0) {
        float m = red[0] / (float)rows;
        float v = red2[0] / (float)rows - m * m;
        mout[f] = m;
        isout[f] = rsqrtf(v + 1e-3f);
    }
}

// ---------------- Kernel D: H2 = LN(dice1(H1) @ W2 + b2) ----------------
__global__ __launch_bounds__(256) void mlp2_kernel(
    const float* __restrict__ H1, const float* __restrict__ m1, const float* __restrict__ is1,
    const float* __restrict__ a1,
    const float* __restrict__ W2, const float* __restrict__ b2, const float* __restrict__ g2,
    const float* __restrict__ be2,
    float* __restrict__ H2)
{
    const int b = blockIdx.x, tid = threadIdx.x;
    __shared__ float d1[N1];
    if (tid < N1) {
        float h  = H1[(size_t)b * N1 + tid];
        float xn = (h - m1[tid]) * is1[tid];
        float p  = 1.f / (1.f + expf(-xn));
        d1[tid]  = h * (p + a1[tid] * (1.f - p));
    }
    __syncthreads();

    float y = 0.f;
    if (tid < N2) {
        y = b2[tid];
        for (int k = 0; k < N1; ++k) y += d1[k] * W2[k * N2 + tid];
    }

    __shared__ float red[256], red2[256];
    float yy = (tid < N2) ? y : 0.f;
    red[tid] = yy; red2[tid] = yy * yy;
    __syncthreads();
    for (int s = 128; s; s >>= 1) {
        if (tid < s) { red[tid] += red[tid + s]; red2[tid] += red2[tid + s]; }
        __syncthreads();
    }
    __shared__ float msh, ish;
    if (tid == 0) {
        float m = red[0] / (float)N2;
        float v = red2[0] / (float)N2 - m * m;
        msh = m; ish = rsqrtf(v + 1e-3f);
    }
    __syncthreads();
    if (tid < N2) H2[(size_t)b * N2 + tid] = g2[tid] * (y - msh) * ish + be2[tid];
}

// ---------------- Kernel F: out = softmax(dice2(H2) @ W3 + b3) ----------------
__global__ __launch_bounds__(256) void head_kernel(
    const float* __restrict__ H2, const float* __restrict__ m2, const float* __restrict__ is2,
    const float* __restrict__ a2,
    const float* __restrict__ W3, const float* __restrict__ b3,
    float* __restrict__ out)
{
    const int b = blockIdx.x * 256 + threadIdx.x;
    if (b >= BB) return;
    float z0 = b3[0], z1 = b3[1];
    for (int k = 0; k < N2; ++k) {
        float h  = H2[(size_t)b * N2 + k];
        float xn = (h - m2[k]) * is2[k];
        float p  = 1.f / (1.f + expf(-xn));
        float d  = h * (p + a2[k] * (1.f - p));
        z0 += d * W3[k * 2 + 0];
        z1 += d * W3[k * 2 + 1];
    }
    float mx = fmaxf(z0, z1);
    float e0 = expf(z0 - mx), e1 = expf(z1 - mx);
    float inv = 1.f / (e0 + e1);
    out[(size_t)b * 2 + 0] = e0 * inv;
    out[(size_t)b * 2 + 1] = e1 * inv;
}

extern "C" void kernel_launch(void* const* d_in, const int* in_sizes, int n_in,
                              void* d_out, int out_size, void* d_ws, size_t ws_size,
                              hipStream_t stream) {
    const int*   ig  = (const int*)  d_in[0];
    const int*   ish = (const int*)  d_in[1];
    const int*   ic  = (const int*)  d_in[2];
    const int*   vg  = (const int*)  d_in[3];
    const int*   vs  = (const int*)  d_in[4];
    const int*   vc  = (const int*)  d_in[5];
    const float* emb = (const float*)d_in[6];
    const float* W1  = (const float*)d_in[7];
    const float* b1  = (const float*)d_in[8];
    const float* g1  = (const float*)d_in[9];
    const float* be1 = (const float*)d_in[10];
    const float* a1  = (const float*)d_in[11];
    const float* W2  = (const float*)d_in[12];
    const float* b2  = (const float*)d_in[13];
    const float* g2  = (const float*)d_in[14];
    const float* be2 = (const float*)d_in[15];
    const float* a2  = (const float*)d_in[16];
    const float* W3  = (const float*)d_in[17];
    const float* b3  = (const float*)d_in[18];

    float* out  = (float*)d_out;                       // [B,2]
    float* Xs   = out + (size_t)BB * 2;                // [B,L,48]
    float* Msk  = Xs + (size_t)BB * LL * DD;           // [B,L]

    float* X    = (float*)d_ws;                        // [B,96]
    float* H1   = X + (size_t)BB * 96;                 // [B,200]
    float* H2v  = H1 + (size_t)BB * N1;                // [B,80]
    float* m1   = H2v + (size_t)BB * N2;               // [200]
    float* is1  = m1 + N1;                             // [200]
    float* m2   = is1 + N1;                            // [80]
    float* is2  = m2 + N2;                             // [80]

    pool_kernel<<<BB, 256, 0, stream>>>(ig, ish, ic, vg, vs, vc, emb, Xs, Msk, X);
    mlp1_kernel<<<BB, 256, 0, stream>>>(X, W1, b1, g1, be1, H1);
    colstats_kernel<<<N1, 256, 0, stream>>>(H1, N1, BB, m1, is1);
    mlp2_kernel<<<BB, 256, 0, stream>>>(H1, m1, is1, a1, W2, b2, g2, be2, H2v);
    colstats_kernel<<<N2, 256, 0, stream>>>(H2v, N2, BB, m2, is2);
    head_kernel<<<(BB + 255) / 256, 256, 0, stream>>>(H2v, m2, is2, a2, W3, b3, out);
}